// Round 1
// baseline (427.021 us; speedup 1.0000x reference)
//
#include <hip/hip_runtime.h>

typedef unsigned short u16;
typedef short bf8 __attribute__((ext_vector_type(8)));
typedef float f4 __attribute__((ext_vector_type(4)));
typedef unsigned short us4 __attribute__((ext_vector_type(4)));

#define DEV static __device__ __forceinline__

DEV u16 f2bf(float x) {
  union { float f; unsigned u; } v; v.f = x;
  unsigned r = v.u + 0x7fffu + ((v.u >> 16) & 1u);  // RNE
  return (u16)(r >> 16);
}
DEV float bf2f(u16 h) {
  union { unsigned u; float f; } v; v.u = ((unsigned)h) << 16;
  return v.f;
}

constexpr int  NSP = 3136;                   // 56*56
constexpr long SZ1 = 2l * 256 * NSP;         // one (b,c,n) tensor, elems
// ws layout (u16 element offsets)
constexpr long OFF_XB  = 0;                  // 2 * SZ1  (bf16 inputs, per modality)
constexpr long OFF_QB  = 2 * SZ1;            // 2 * SZ1  (B,NH,N,HD) per mha-source
constexpr long OFF_KB  = 4 * SZ1;
constexpr long OFF_VB  = 6 * SZ1;            // conv layout (b,c,n) = V^T
constexpr long OFF_ATT = 8 * SZ1;            // (b, 512, n): [rgb_att ; depth_att]
constexpr long OFF_H   = 10 * SZ1;           // (b, 256, n)
constexpr long OFF_WC  = 11 * SZ1;           // 2 x 768 x 256
constexpr long OFF_WF1 = OFF_WC + 2l * 768 * 256;
constexpr long OFF_WF2 = OFF_WF1 + 256l * 512;
constexpr long END_BF16 = OFF_WF2 + 256l * 256;

// ---------------- input conversion: f32 -> bf16 ----------------
__global__ __launch_bounds__(256) void k_cvt_x(const float* __restrict__ rgb,
                                               const float* __restrict__ dep,
                                               u16* __restrict__ xb) {
  const int zz = blockIdx.y;
  const float* s = zz ? dep : rgb;
  const long i = ((long)blockIdx.x * 256 + threadIdx.x) * 4;
  f4 v = *(const f4*)(s + i);
  us4 o; o.x = f2bf(v.x); o.y = f2bf(v.y); o.z = f2bf(v.z); o.w = f2bf(v.w);
  *(us4*)(xb + (long)zz * SZ1 + i) = o;
}

// ---------------- weight prep: concat + bf16 ----------------
__global__ __launch_bounds__(256) void k_prep(
    const float* __restrict__ wq_rd, const float* __restrict__ wk_r, const float* __restrict__ wv_r,
    const float* __restrict__ wq_dr, const float* __restrict__ wk_d, const float* __restrict__ wv_d,
    const float* __restrict__ wf1, const float* __restrict__ wf2,
    const float* __restrict__ bq_rd, const float* __restrict__ bk_r, const float* __restrict__ bv_r,
    const float* __restrict__ bq_dr, const float* __restrict__ bk_d, const float* __restrict__ bv_d,
    u16* __restrict__ wsb, float* __restrict__ bcat) {
  long idx = (long)blockIdx.x * 256 + threadIdx.x;
  const long WCN = 2l * 768 * 256;  // 393216
  if (idx < WCN) {
    int mod = idx >= 768l * 256;
    long rr = idx - (mod ? 768l * 256 : 0);
    int row = (int)(rr >> 8), col = (int)(rr & 255);
    int seg = row >> 8, r2 = row & 255;
    const float* src;
    if (!mod) src = seg == 0 ? wq_rd : (seg == 1 ? wk_r : wv_r);
    else      src = seg == 0 ? wq_dr : (seg == 1 ? wk_d : wv_d);
    wsb[OFF_WC + idx] = f2bf(src[r2 * 256 + col]);
    return;
  }
  long j = idx - WCN;
  if (j < 256l * 512) { wsb[OFF_WF1 + j] = f2bf(wf1[j]); return; }
  j -= 256l * 512;
  if (j < 256l * 256) { wsb[OFF_WF2 + j] = f2bf(wf2[j]); return; }
  j -= 256l * 256;
  if (j < 1536) {
    int mod = j >= 768;
    int row = (int)j - (mod ? 768 : 0);
    int seg = row >> 8, r2 = row & 255;
    const float* src;
    if (!mod) src = seg == 0 ? bq_rd : (seg == 1 ? bk_r : bv_r);
    else      src = seg == 0 ? bq_dr : (seg == 1 ? bk_d : bv_d);
    bcat[j] = src[r2];
  }
}

// ---------------- generic GEMM: out[o][n] = act(sum_c W[o][c] In[c][n] + b) ----------------
// EPI 0: QKV projections (z = b*2+mod), M=768, writes Q/K (b,h,n,hd) and V (b,c,n)
// EPI 1: fusion1 (z = b), M=256, K=512, bias+BN+ReLU -> h bf16
// EPI 2: fusion2 (z = b), M=256, K=256, bias -> f32 d_out
template <int KDIM, int EPI>
__global__ __launch_bounds__(256) void k_gemm(
    u16* __restrict__ wsb, const float* __restrict__ bcat,
    const float* __restrict__ bf1, const float* __restrict__ gamma,
    const float* __restrict__ beta, const float* __restrict__ bf2,
    float* __restrict__ outf) {
  __shared__ u16 xT[64 * 40];  // [n_local][c_local], stride 40 (80B: 16B-aligned rows, 2-way banks)
  const int tid = threadIdx.x;
  const int lane = tid & 63, wid = tid >> 6;
  const int g = lane >> 4, r = lane & 15;
  const int wm = wid >> 1, wn = wid & 1;
  const int n0 = blockIdx.x * 64;
  const int m0 = blockIdx.y * 128;
  const int z = blockIdx.z;

  int b = 0, mod = 0;
  const u16* In; const u16* W;
  if constexpr (EPI == 0) {
    mod = z & 1; b = z >> 1;
    In = wsb + OFF_XB + mod * SZ1 + (long)b * 256 * NSP;
    W  = wsb + OFF_WC + (long)mod * 768 * 256;
  } else if constexpr (EPI == 1) {
    b = z;
    In = wsb + OFF_ATT + (long)b * 512 * NSP;
    W  = wsb + OFF_WF1;
  } else {
    b = z;
    In = wsb + OFF_H + (long)b * 256 * NSP;
    W  = wsb + OFF_WF2;
  }

  const int M0 = m0 + wm * 64;
  const f4 zero4 = {0.f, 0.f, 0.f, 0.f};
  f4 acc[4][2];
#pragma unroll
  for (int i = 0; i < 4; ++i)
#pragma unroll
    for (int j = 0; j < 2; ++j) acc[i][j] = zero4;

  for (int kc = 0; kc < KDIM; kc += 32) {
    __syncthreads();
#pragma unroll
    for (int p = 0; p < 2; ++p) {
      int idx = tid + p * 256;
      int c = idx >> 4;             // 0..31
      int n4 = (idx & 15) << 2;     // 0..60
      us4 v = *(const us4*)(In + (long)(kc + c) * NSP + n0 + n4);
      xT[(n4 + 0) * 40 + c] = v.x;
      xT[(n4 + 1) * 40 + c] = v.y;
      xT[(n4 + 2) * 40 + c] = v.z;
      xT[(n4 + 3) * 40 + c] = v.w;
    }
    __syncthreads();
    bf8 aw[4];
#pragma unroll
    for (int i = 0; i < 4; ++i)
      aw[i] = *(const bf8*)(W + (long)(M0 + i * 16 + r) * KDIM + kc + g * 8);
    bf8 bx[2];
#pragma unroll
    for (int jn = 0; jn < 2; ++jn)
      bx[jn] = *(const bf8*)(xT + (wn * 32 + jn * 16 + r) * 40 + g * 8);
#pragma unroll
    for (int i = 0; i < 4; ++i)
#pragma unroll
      for (int jn = 0; jn < 2; ++jn)
        acc[i][jn] = __builtin_amdgcn_mfma_f32_16x16x32_bf16(aw[i], bx[jn], acc[i][jn], 0, 0, 0);
  }

  const int seg = M0 >> 8;  // uniform per wave
#pragma unroll
  for (int i = 0; i < 4; ++i) {
    const int orow = M0 + i * 16 + 4 * g;  // + reg
#pragma unroll
    for (int jn = 0; jn < 2; ++jn) {
      const int n = n0 + wn * 32 + jn * 16 + r;
      f4 a = acc[i][jn];
      if constexpr (EPI == 0) {
        const int ol = orow & 255;
        const float* bs = bcat + mod * 768 + seg * 256 + ol;
        float a0 = a.x + bs[0], a1 = a.y + bs[1], a2 = a.z + bs[2], a3 = a.w + bs[3];
        if (seg < 2) {
          const long off = (seg == 0 ? OFF_QB : OFF_KB) + mod * SZ1;
          const int hh = ol >> 5, hd = ol & 31;
          us4 pk; pk.x = f2bf(a0); pk.y = f2bf(a1); pk.z = f2bf(a2); pk.w = f2bf(a3);
          *(us4*)(wsb + off + ((long)((b * 8 + hh) * NSP + n)) * 32 + hd) = pk;
        } else {
          u16* dst = wsb + OFF_VB + mod * SZ1 + ((long)(b * 256 + ol)) * NSP + n;
          dst[0] = f2bf(a0); dst[NSP] = f2bf(a1);
          dst[2 * NSP] = f2bf(a2); dst[3 * NSP] = f2bf(a3);
        }
      } else if constexpr (EPI == 1) {
#pragma unroll
        for (int q = 0; q < 4; ++q) {
          const int o = orow + q;
          float v = (a[q] + bf1[o]) * (gamma[o] * 0.9999950000374994f) + beta[o];
          v = fmaxf(v, 0.f);
          wsb[OFF_H + (long)(b * 256 + o) * NSP + n] = f2bf(v);
        }
      } else {
#pragma unroll
        for (int q = 0; q < 4; ++q) {
          const int o = orow + q;
          outf[(long)(b * 256 + o) * NSP + n] = a[q] + bf2[o];
        }
      }
    }
  }
}

// ---------------- flash attention ----------------
// grid (49 qtiles, 16 bh, 2 mha); 4 waves/block, 16 q-rows/wave, KVBLK=32
__global__ __launch_bounds__(256) void k_attn(u16* __restrict__ wsb) {
  const int m = blockIdx.z;
  const int bh = blockIdx.y;
  const int b = bh >> 3, h = bh & 7;
  const int lane = threadIdx.x & 63, wid = threadIdx.x >> 6;
  const int g = lane >> 4, r = lane & 15;
  const int q0 = blockIdx.x * 64 + wid * 16;

  const u16* Q = wsb + OFF_QB + (long)m * SZ1;
  const u16* K = wsb + OFF_KB + (long)(1 - m) * SZ1;
  const u16* V = wsb + OFF_VB + (long)(1 - m) * SZ1;
  const long rowbase = (long)bh * NSP;

  const bf8 qf = *(const bf8*)(Q + (rowbase + q0 + r) * 32 + g * 8);
  // sigma-permuted K row base: row = 8*(r>>2) + (r&3); tile1 adds +4
  const u16* kp = K + (rowbase + ((r >> 2) << 3) + (r & 3)) * 32 + g * 8;
  const u16* vp0 = V + ((long)(b * 256 + h * 32 + r)) * NSP;
  const u16* vp1 = vp0 + (long)16 * NSP;

  const f4 zero4 = {0.f, 0.f, 0.f, 0.f};
  f4 o0 = zero4, o1 = zero4;
  float mr = -3.0e38f, l = 0.f;
  const float SC = 0.2550205145980166f;  // log2(e)/sqrt(32)

  for (int kv = 0; kv < NSP; kv += 32) {
    bf8 kf0 = *(const bf8*)(kp + (long)kv * 32);
    bf8 kf1 = *(const bf8*)(kp + (long)(kv + 4) * 32);
    f4 s0 = __builtin_amdgcn_mfma_f32_16x16x32_bf16(kf0, qf, zero4, 0, 0, 0);
    f4 s1 = __builtin_amdgcn_mfma_f32_16x16x32_bf16(kf1, qf, zero4, 0, 0, 0);
    float t0 = fmaxf(fmaxf(s0.x, s0.y), fmaxf(s0.z, s0.w));
    float t1 = fmaxf(fmaxf(s1.x, s1.y), fmaxf(s1.z, s1.w));
    float tm = fmaxf(t0, t1) * SC;
    tm = fmaxf(tm, __shfl_xor(tm, 16, 64));
    tm = fmaxf(tm, __shfl_xor(tm, 32, 64));
    const float mn = fmaxf(mr, tm);
    const float corr = exp2f(mr - mn);
    mr = mn;
    float p0 = exp2f(s0.x * SC - mn), p1 = exp2f(s0.y * SC - mn);
    float p2 = exp2f(s0.z * SC - mn), p3 = exp2f(s0.w * SC - mn);
    float p4 = exp2f(s1.x * SC - mn), p5 = exp2f(s1.y * SC - mn);
    float p6 = exp2f(s1.z * SC - mn), p7 = exp2f(s1.w * SC - mn);
    l = l * corr + ((p0 + p1) + (p2 + p3)) + ((p4 + p5) + (p6 + p7));
    o0 *= corr; o1 *= corr;
    bf8 pb;
    pb[0] = (short)f2bf(p0); pb[1] = (short)f2bf(p1);
    pb[2] = (short)f2bf(p2); pb[3] = (short)f2bf(p3);
    pb[4] = (short)f2bf(p4); pb[5] = (short)f2bf(p5);
    pb[6] = (short)f2bf(p6); pb[7] = (short)f2bf(p7);
    bf8 v0 = *(const bf8*)(vp0 + kv + g * 8);
    bf8 v1 = *(const bf8*)(vp1 + kv + g * 8);
    o0 = __builtin_amdgcn_mfma_f32_16x16x32_bf16(v0, pb, o0, 0, 0, 0);
    o1 = __builtin_amdgcn_mfma_f32_16x16x32_bf16(v1, pb, o1, 0, 0, 0);
  }
  l += __shfl_xor(l, 16, 64);
  l += __shfl_xor(l, 32, 64);
  const float inv = 1.0f / l;
  o0 *= inv; o1 *= inv;
  u16* dp = wsb + OFF_ATT + ((long)(b * 512 + m * 256 + h * 32 + 4 * g)) * NSP + q0 + r;
#pragma unroll
  for (int q = 0; q < 4; ++q) {
    dp[(long)q * NSP] = f2bf(o0[q]);
    dp[(long)(16 + q) * NSP] = f2bf(o1[q]);
  }
}

// ---------------- attention map ----------------
__global__ __launch_bounds__(256) void k_amap_red(const u16* __restrict__ wsb,
                                                  float* __restrict__ att2) {
  const int bh = blockIdx.x;
  const int b = bh >> 3;
  const int t = threadIdx.x;
  const int d = t & 31, ns = t >> 5;
  const u16* q = wsb + OFF_QB;            // qb[0] = Q_rgb (b,h,n,hd)
  const u16* k = wsb + OFF_KB + SZ1;      // kb[1] = K_depth
  const long base = (long)bh * NSP * 32;
  float qs = 0.f, ks = 0.f;
  for (int n = ns; n < NSP; n += 8) {
    qs += bf2f(q[base + (long)n * 32 + d]);
    ks += bf2f(k[base + (long)n * 32 + d]);
  }
  __shared__ float sq[256], sk[256];
  sq[t] = qs; sk[t] = ks;
  __syncthreads();
  if (t < 32) {
#pragma unroll
    for (int j = 1; j < 8; ++j) { qs += sq[t + 32 * j]; ks += sk[t + 32 * j]; }
    float dot = qs * ks;
#pragma unroll
    for (int off = 16; off; off >>= 1) dot += __shfl_xor(dot, off, 64);
    if (t == 0) atomicAdd(att2 + b, dot * (1.0f / (8.0f * 3136.0f * 3136.0f)));
  }
}

__global__ void k_amap_wr(const float* __restrict__ att2, float* __restrict__ outf) {
  const int b = blockIdx.y;
  const int i = blockIdx.x * 256 + threadIdx.x;
  if (i < NSP) outf[2l * 256 * NSP + (long)b * NSP + i] = att2[b];
}

// ---------------- launch ----------------
extern "C" void kernel_launch(void* const* d_in, const int* in_sizes, int n_in,
                              void* d_out, int out_size, void* d_ws, size_t ws_size,
                              hipStream_t stream) {
  const float* rgb   = (const float*)d_in[0];
  const float* dep   = (const float*)d_in[1];
  const float* Wq_rd = (const float*)d_in[2];
  const float* bq_rd = (const float*)d_in[3];
  const float* Wk_d  = (const float*)d_in[4];
  const float* bk_d  = (const float*)d_in[5];
  const float* Wv_d  = (const float*)d_in[6];
  const float* bv_d  = (const float*)d_in[7];
  const float* Wq_dr = (const float*)d_in[8];
  const float* bq_dr = (const float*)d_in[9];
  const float* Wk_r  = (const float*)d_in[10];
  const float* bk_r  = (const float*)d_in[11];
  const float* Wv_r  = (const float*)d_in[12];
  const float* bv_r  = (const float*)d_in[13];
  const float* Wf1   = (const float*)d_in[14];
  const float* bf1   = (const float*)d_in[15];
  const float* gamma = (const float*)d_in[16];
  const float* beta  = (const float*)d_in[17];
  const float* Wf2   = (const float*)d_in[18];
  const float* bf2   = (const float*)d_in[19];
  float* out = (float*)d_out;

  u16* wsb = (u16*)d_ws;
  float* wsf = (float*)((char*)d_ws + (size_t)END_BF16 * 2);
  float* att2 = wsf;
  float* bcat = wsf + 4;
  const size_t needed = (size_t)END_BF16 * 2 + (4 + 1536) * sizeof(float);
  if (ws_size < needed) return;  // ws too small; nothing safe to do

  hipMemsetAsync(att2, 0, 2 * sizeof(float), stream);
  k_cvt_x<<<dim3(1568, 2), 256, 0, stream>>>(rgb, dep, wsb);
  k_prep<<<2310, 256, 0, stream>>>(Wq_rd, Wk_r, Wv_r, Wq_dr, Wk_d, Wv_d, Wf1, Wf2,
                                   bq_rd, bk_r, bv_r, bq_dr, bk_d, bv_d, wsb, bcat);
  k_gemm<256, 0><<<dim3(49, 6, 4), 256, 0, stream>>>(wsb, bcat, nullptr, nullptr, nullptr, nullptr, nullptr);
  k_attn<<<dim3(49, 16, 2), 256, 0, stream>>>(wsb);
  k_amap_red<<<16, 256, 0, stream>>>(wsb, att2);
  k_amap_wr<<<dim3(13, 2), 256, 0, stream>>>(att2, out);
  k_gemm<512, 1><<<dim3(49, 2, 2), 256, 0, stream>>>(wsb, nullptr, bf1, gamma, beta, nullptr, nullptr);
  k_gemm<256, 2><<<dim3(49, 2, 2), 256, 0, stream>>>(wsb, nullptr, nullptr, nullptr, nullptr, bf2, out);
}

// Round 2
// 317.468 us; speedup vs baseline: 1.3451x; 1.3451x over previous
//
#include <hip/hip_runtime.h>

typedef unsigned short u16;
typedef short bf8 __attribute__((ext_vector_type(8)));
typedef float f4 __attribute__((ext_vector_type(4)));
typedef unsigned short us4 __attribute__((ext_vector_type(4)));

#define DEV static __device__ __forceinline__

DEV u16 f2bf(float x) {
  union { float f; unsigned u; } v; v.f = x;
  unsigned r = v.u + 0x7fffu + ((v.u >> 16) & 1u);  // RNE
  return (u16)(r >> 16);
}
DEV float bf2f(u16 h) {
  union { unsigned u; float f; } v; v.u = ((unsigned)h) << 16;
  return v.f;
}

constexpr int  NSP = 3136;                   // 56*56
constexpr long SZ1 = 2l * 256 * NSP;         // one (b,c,n) tensor, elems
constexpr float SCQ = 0.2550205145980166f;   // log2(e)/sqrt(32), folded into Q
// ws layout (u16 element offsets)
constexpr long OFF_XB  = 0;                  // 2 * SZ1  (bf16 inputs, per modality)
constexpr long OFF_QB  = 2 * SZ1;            // 2 * SZ1  (B,NH,N,HD) per mha-source
constexpr long OFF_KB  = 4 * SZ1;
constexpr long OFF_VB  = 6 * SZ1;            // conv layout (b,c,n) = V^T
constexpr long OFF_ATT = 8 * SZ1;            // (b, 512, n): [rgb_att ; depth_att]
constexpr long OFF_H   = 10 * SZ1;           // (b, 256, n)
constexpr long OFF_WC  = 11 * SZ1;           // 2 x 768 x 256
constexpr long OFF_WF1 = OFF_WC + 2l * 768 * 256;
constexpr long OFF_WF2 = OFF_WF1 + 256l * 512;
constexpr long END_BF16 = OFF_WF2 + 256l * 256;

// ---------------- input conversion: f32 -> bf16 ----------------
__global__ __launch_bounds__(256) void k_cvt_x(const float* __restrict__ rgb,
                                               const float* __restrict__ dep,
                                               u16* __restrict__ xb) {
  const int zz = blockIdx.y;
  const float* s = zz ? dep : rgb;
  const long i = ((long)blockIdx.x * 256 + threadIdx.x) * 4;
  f4 v = *(const f4*)(s + i);
  us4 o; o.x = f2bf(v.x); o.y = f2bf(v.y); o.z = f2bf(v.z); o.w = f2bf(v.w);
  *(us4*)(xb + (long)zz * SZ1 + i) = o;
}

// ---------------- weight prep: concat + bf16 ----------------
__global__ __launch_bounds__(256) void k_prep(
    const float* __restrict__ wq_rd, const float* __restrict__ wk_r, const float* __restrict__ wv_r,
    const float* __restrict__ wq_dr, const float* __restrict__ wk_d, const float* __restrict__ wv_d,
    const float* __restrict__ wf1, const float* __restrict__ wf2,
    const float* __restrict__ bq_rd, const float* __restrict__ bk_r, const float* __restrict__ bv_r,
    const float* __restrict__ bq_dr, const float* __restrict__ bk_d, const float* __restrict__ bv_d,
    u16* __restrict__ wsb, float* __restrict__ bcat) {
  long idx = (long)blockIdx.x * 256 + threadIdx.x;
  const long WCN = 2l * 768 * 256;  // 393216
  if (idx < WCN) {
    int mod = idx >= 768l * 256;
    long rr = idx - (mod ? 768l * 256 : 0);
    int row = (int)(rr >> 8), col = (int)(rr & 255);
    int seg = row >> 8, r2 = row & 255;
    const float* src;
    if (!mod) src = seg == 0 ? wq_rd : (seg == 1 ? wk_r : wv_r);
    else      src = seg == 0 ? wq_dr : (seg == 1 ? wk_d : wv_d);
    wsb[OFF_WC + idx] = f2bf(src[r2 * 256 + col]);
    return;
  }
  long j = idx - WCN;
  if (j < 256l * 512) { wsb[OFF_WF1 + j] = f2bf(wf1[j]); return; }
  j -= 256l * 512;
  if (j < 256l * 256) { wsb[OFF_WF2 + j] = f2bf(wf2[j]); return; }
  j -= 256l * 256;
  if (j < 1536) {
    int mod = j >= 768;
    int row = (int)j - (mod ? 768 : 0);
    int seg = row >> 8, r2 = row & 255;
    const float* src;
    if (!mod) src = seg == 0 ? bq_rd : (seg == 1 ? bk_r : bv_r);
    else      src = seg == 0 ? bq_dr : (seg == 1 ? bk_d : bv_d);
    bcat[j] = src[r2];
  }
}

// ---------------- generic GEMM: out[o][n] = act(sum_c W[o][c] In[c][n] + b) ----------------
// EPI 0: QKV projections (z = b*2+mod), M=768, writes Q (scaled by SCQ) /K (b,h,n,hd) and V (b,c,n)
// EPI 1: fusion1 (z = b), M=256, K=512, bias+BN+ReLU -> h bf16
// EPI 2: fusion2 (z = b), M=256, K=256, bias -> f32 d_out
template <int KDIM, int EPI>
__global__ __launch_bounds__(256) void k_gemm(
    u16* __restrict__ wsb, const float* __restrict__ bcat,
    const float* __restrict__ bf1, const float* __restrict__ gamma,
    const float* __restrict__ beta, const float* __restrict__ bf2,
    float* __restrict__ outf) {
  __shared__ u16 xT[64 * 40];  // [n_local][c_local], stride 40
  const int tid = threadIdx.x;
  const int lane = tid & 63, wid = tid >> 6;
  const int g = lane >> 4, r = lane & 15;
  const int wm = wid >> 1, wn = wid & 1;
  const int n0 = blockIdx.x * 64;
  const int m0 = blockIdx.y * 128;
  const int z = blockIdx.z;

  int b = 0, mod = 0;
  const u16* In; const u16* W;
  if constexpr (EPI == 0) {
    mod = z & 1; b = z >> 1;
    In = wsb + OFF_XB + mod * SZ1 + (long)b * 256 * NSP;
    W  = wsb + OFF_WC + (long)mod * 768 * 256;
  } else if constexpr (EPI == 1) {
    b = z;
    In = wsb + OFF_ATT + (long)b * 512 * NSP;
    W  = wsb + OFF_WF1;
  } else {
    b = z;
    In = wsb + OFF_H + (long)b * 256 * NSP;
    W  = wsb + OFF_WF2;
  }

  const int M0 = m0 + wm * 64;
  const f4 zero4 = {0.f, 0.f, 0.f, 0.f};
  f4 acc[4][2];
#pragma unroll
  for (int i = 0; i < 4; ++i)
#pragma unroll
    for (int j = 0; j < 2; ++j) acc[i][j] = zero4;

  for (int kc = 0; kc < KDIM; kc += 32) {
    __syncthreads();
#pragma unroll
    for (int p = 0; p < 2; ++p) {
      int idx = tid + p * 256;
      int c = idx >> 4;             // 0..31
      int n4 = (idx & 15) << 2;     // 0..60
      us4 v = *(const us4*)(In + (long)(kc + c) * NSP + n0 + n4);
      xT[(n4 + 0) * 40 + c] = v.x;
      xT[(n4 + 1) * 40 + c] = v.y;
      xT[(n4 + 2) * 40 + c] = v.z;
      xT[(n4 + 3) * 40 + c] = v.w;
    }
    __syncthreads();
    bf8 aw[4];
#pragma unroll
    for (int i = 0; i < 4; ++i)
      aw[i] = *(const bf8*)(W + (long)(M0 + i * 16 + r) * KDIM + kc + g * 8);
    bf8 bx[2];
#pragma unroll
    for (int jn = 0; jn < 2; ++jn)
      bx[jn] = *(const bf8*)(xT + (wn * 32 + jn * 16 + r) * 40 + g * 8);
#pragma unroll
    for (int i = 0; i < 4; ++i)
#pragma unroll
      for (int jn = 0; jn < 2; ++jn)
        acc[i][jn] = __builtin_amdgcn_mfma_f32_16x16x32_bf16(aw[i], bx[jn], acc[i][jn], 0, 0, 0);
  }

  const int seg = M0 >> 8;  // uniform per wave
#pragma unroll
  for (int i = 0; i < 4; ++i) {
    const int orow = M0 + i * 16 + 4 * g;  // + reg
#pragma unroll
    for (int jn = 0; jn < 2; ++jn) {
      const int n = n0 + wn * 32 + jn * 16 + r;
      f4 a = acc[i][jn];
      if constexpr (EPI == 0) {
        const int ol = orow & 255;
        const float* bs = bcat + mod * 768 + seg * 256 + ol;
        const float qs = (seg == 0) ? SCQ : 1.0f;   // fold softmax scale into Q
        float a0 = (a.x + bs[0]) * qs, a1 = (a.y + bs[1]) * qs;
        float a2 = (a.z + bs[2]) * qs, a3 = (a.w + bs[3]) * qs;
        if (seg < 2) {
          const long off = (seg == 0 ? OFF_QB : OFF_KB) + mod * SZ1;
          const int hh = ol >> 5, hd = ol & 31;
          us4 pk; pk.x = f2bf(a0); pk.y = f2bf(a1); pk.z = f2bf(a2); pk.w = f2bf(a3);
          *(us4*)(wsb + off + ((long)((b * 8 + hh) * NSP + n)) * 32 + hd) = pk;
        } else {
          u16* dst = wsb + OFF_VB + mod * SZ1 + ((long)(b * 256 + ol)) * NSP + n;
          dst[0] = f2bf(a0); dst[NSP] = f2bf(a1);
          dst[2 * NSP] = f2bf(a2); dst[3 * NSP] = f2bf(a3);
        }
      } else if constexpr (EPI == 1) {
#pragma unroll
        for (int q = 0; q < 4; ++q) {
          const int o = orow + q;
          float v = (a[q] + bf1[o]) * (gamma[o] * 0.9999950000374994f) + beta[o];
          v = fmaxf(v, 0.f);
          wsb[OFF_H + (long)(b * 256 + o) * NSP + n] = f2bf(v);
        }
      } else {
#pragma unroll
        for (int q = 0; q < 4; ++q) {
          const int o = orow + q;
          outf[(long)(b * 256 + o) * NSP + n] = a[q] + bf2[o];
        }
      }
    }
  }
}

// ---------------- flash attention (no-max-shift softmax; Q pre-scaled) ----------------
// grid (49 qtiles, 16 bh, 2 mha); 2 waves/block, 32 q-rows/wave, KVBLK=64
DEV bf8 pack_p(f4 s0, f4 s1) {
  union { unsigned u[4]; bf8 v; } p;
  float a0 = __builtin_amdgcn_exp2f(s0.x), a1 = __builtin_amdgcn_exp2f(s0.y);
  float a2 = __builtin_amdgcn_exp2f(s0.z), a3 = __builtin_amdgcn_exp2f(s0.w);
  float a4 = __builtin_amdgcn_exp2f(s1.x), a5 = __builtin_amdgcn_exp2f(s1.y);
  float a6 = __builtin_amdgcn_exp2f(s1.z), a7 = __builtin_amdgcn_exp2f(s1.w);
  asm("v_cvt_pk_bf16_f32 %0, %1, %2" : "=v"(p.u[0]) : "v"(a0), "v"(a1));
  asm("v_cvt_pk_bf16_f32 %0, %1, %2" : "=v"(p.u[1]) : "v"(a2), "v"(a3));
  asm("v_cvt_pk_bf16_f32 %0, %1, %2" : "=v"(p.u[2]) : "v"(a4), "v"(a5));
  asm("v_cvt_pk_bf16_f32 %0, %1, %2" : "=v"(p.u[3]) : "v"(a6), "v"(a7));
  return p.v;
}

__global__ __launch_bounds__(128) void k_attn(u16* __restrict__ wsb) {
  const int m = blockIdx.z;
  const int bh = blockIdx.y;
  const int b = bh >> 3, h = bh & 7;
  const int lane = threadIdx.x & 63, wid = threadIdx.x >> 6;
  const int g = lane >> 4, r = lane & 15;
  const int q0 = blockIdx.x * 64 + wid * 32;

  const u16* Q = wsb + OFF_QB + (long)m * SZ1;
  const u16* K = wsb + OFF_KB + (long)(1 - m) * SZ1;
  const u16* V = wsb + OFF_VB + (long)(1 - m) * SZ1;
  const long rowbase = (long)bh * NSP;

  const bf8 qfA = *(const bf8*)(Q + (rowbase + q0 + r) * 32 + g * 8);
  const bf8 qfB = *(const bf8*)(Q + (rowbase + q0 + 16 + r) * 32 + g * 8);
  // sigma-permuted K row base: row = 8*(r>>2) + (r&3)
  const u16* kp = K + (rowbase + ((r >> 2) << 3) + (r & 3)) * 32 + g * 8;
  const u16* vp = V + ((long)(b * 256 + h * 32 + r)) * NSP + g * 8;

  bf8 ones;
#pragma unroll
  for (int j = 0; j < 8; ++j) ones[j] = (short)0x3F80;  // bf16 1.0

  const f4 zero4 = {0.f, 0.f, 0.f, 0.f};
  f4 oA0 = zero4, oA1 = zero4, oB0 = zero4, oB1 = zero4;
  f4 lA = zero4, lB = zero4;

  for (int kv = 0; kv < NSP; kv += 64) {
    const bf8 kf0 = *(const bf8*)(kp);
    const bf8 kf1 = *(const bf8*)(kp + 128);
    const bf8 kf2 = *(const bf8*)(kp + 1024);
    const bf8 kf3 = *(const bf8*)(kp + 1152);
    kp += 2048;
    const bf8 v0a = *(const bf8*)(vp);
    const bf8 v0b = *(const bf8*)(vp + 32);
    const bf8 v1a = *(const bf8*)(vp + 16 * NSP);
    const bf8 v1b = *(const bf8*)(vp + 16 * NSP + 32);
    vp += 64;

    // group A (q = q0 + r)
    {
      f4 s0 = __builtin_amdgcn_mfma_f32_16x16x32_bf16(kf0, qfA, zero4, 0, 0, 0);
      f4 s1 = __builtin_amdgcn_mfma_f32_16x16x32_bf16(kf1, qfA, zero4, 0, 0, 0);
      f4 s2 = __builtin_amdgcn_mfma_f32_16x16x32_bf16(kf2, qfA, zero4, 0, 0, 0);
      f4 s3 = __builtin_amdgcn_mfma_f32_16x16x32_bf16(kf3, qfA, zero4, 0, 0, 0);
      bf8 p0 = pack_p(s0, s1);   // kv .. kv+31
      bf8 p1 = pack_p(s2, s3);   // kv+32 .. kv+63
      lA  = __builtin_amdgcn_mfma_f32_16x16x32_bf16(ones, p0, lA, 0, 0, 0);
      lA  = __builtin_amdgcn_mfma_f32_16x16x32_bf16(ones, p1, lA, 0, 0, 0);
      oA0 = __builtin_amdgcn_mfma_f32_16x16x32_bf16(v0a, p0, oA0, 0, 0, 0);
      oA0 = __builtin_amdgcn_mfma_f32_16x16x32_bf16(v0b, p1, oA0, 0, 0, 0);
      oA1 = __builtin_amdgcn_mfma_f32_16x16x32_bf16(v1a, p0, oA1, 0, 0, 0);
      oA1 = __builtin_amdgcn_mfma_f32_16x16x32_bf16(v1b, p1, oA1, 0, 0, 0);
    }
    // group B (q = q0 + 16 + r)
    {
      f4 s0 = __builtin_amdgcn_mfma_f32_16x16x32_bf16(kf0, qfB, zero4, 0, 0, 0);
      f4 s1 = __builtin_amdgcn_mfma_f32_16x16x32_bf16(kf1, qfB, zero4, 0, 0, 0);
      f4 s2 = __builtin_amdgcn_mfma_f32_16x16x32_bf16(kf2, qfB, zero4, 0, 0, 0);
      f4 s3 = __builtin_amdgcn_mfma_f32_16x16x32_bf16(kf3, qfB, zero4, 0, 0, 0);
      bf8 p0 = pack_p(s0, s1);
      bf8 p1 = pack_p(s2, s3);
      lB  = __builtin_amdgcn_mfma_f32_16x16x32_bf16(ones, p0, lB, 0, 0, 0);
      lB  = __builtin_amdgcn_mfma_f32_16x16x32_bf16(ones, p1, lB, 0, 0, 0);
      oB0 = __builtin_amdgcn_mfma_f32_16x16x32_bf16(v0a, p0, oB0, 0, 0, 0);
      oB0 = __builtin_amdgcn_mfma_f32_16x16x32_bf16(v0b, p1, oB0, 0, 0, 0);
      oB1 = __builtin_amdgcn_mfma_f32_16x16x32_bf16(v1a, p0, oB1, 0, 0, 0);
      oB1 = __builtin_amdgcn_mfma_f32_16x16x32_bf16(v1b, p1, oB1, 0, 0, 0);
    }
  }

  const float invA = 1.0f / lA.x;  // lane (r,g): l for q-row q0+r (all regs identical)
  const float invB = 1.0f / lB.x;
  oA0 *= invA; oA1 *= invA; oB0 *= invB; oB1 *= invB;

  u16* dp = wsb + OFF_ATT + ((long)(b * 512 + m * 256 + h * 32 + 4 * g)) * NSP + q0 + r;
#pragma unroll
  for (int q = 0; q < 4; ++q) {
    dp[(long)q * NSP]             = f2bf(oA0[q]);
    dp[(long)(16 + q) * NSP]      = f2bf(oA1[q]);
    dp[(long)q * NSP + 16]        = f2bf(oB0[q]);
    dp[(long)(16 + q) * NSP + 16] = f2bf(oB1[q]);
  }
}

// ---------------- attention map ----------------
__global__ __launch_bounds__(256) void k_amap_red(const u16* __restrict__ wsb,
                                                  float* __restrict__ att2) {
  const int bh = blockIdx.x;
  const int b = bh >> 3;
  const int t = threadIdx.x;
  const int d = t & 31, ns = t >> 5;
  const u16* q = wsb + OFF_QB;            // qb[0] = Q_rgb (b,h,n,hd), scaled by SCQ
  const u16* k = wsb + OFF_KB + SZ1;      // kb[1] = K_depth
  const long base = (long)bh * NSP * 32;
  float qs = 0.f, ks = 0.f;
  for (int n = ns; n < NSP; n += 8) {
    qs += bf2f(q[base + (long)n * 32 + d]);
    ks += bf2f(k[base + (long)n * 32 + d]);
  }
  __shared__ float sq[256], sk[256];
  sq[t] = qs; sk[t] = ks;
  __syncthreads();
  if (t < 32) {
#pragma unroll
    for (int j = 1; j < 8; ++j) { qs += sq[t + 32 * j]; ks += sk[t + 32 * j]; }
    float dot = qs * ks;
#pragma unroll
    for (int off = 16; off; off >>= 1) dot += __shfl_xor(dot, off, 64);
    if (t == 0) atomicAdd(att2 + b, dot * (1.0f / (8.0f * 3136.0f * 3136.0f * SCQ)));
  }
}

__global__ void k_amap_wr(const float* __restrict__ att2, float* __restrict__ outf) {
  const int b = blockIdx.y;
  const int i = blockIdx.x * 256 + threadIdx.x;
  if (i < NSP) outf[2l * 256 * NSP + (long)b * NSP + i] = att2[b];
}

// ---------------- launch ----------------
extern "C" void kernel_launch(void* const* d_in, const int* in_sizes, int n_in,
                              void* d_out, int out_size, void* d_ws, size_t ws_size,
                              hipStream_t stream) {
  const float* rgb   = (const float*)d_in[0];
  const float* dep   = (const float*)d_in[1];
  const float* Wq_rd = (const float*)d_in[2];
  const float* bq_rd = (const float*)d_in[3];
  const float* Wk_d  = (const float*)d_in[4];
  const float* bk_d  = (const float*)d_in[5];
  const float* Wv_d  = (const float*)d_in[6];
  const float* bv_d  = (const float*)d_in[7];
  const float* Wq_dr = (const float*)d_in[8];
  const float* bq_dr = (const float*)d_in[9];
  const float* Wk_r  = (const float*)d_in[10];
  const float* bk_r  = (const float*)d_in[11];
  const float* Wv_r  = (const float*)d_in[12];
  const float* bv_r  = (const float*)d_in[13];
  const float* Wf1   = (const float*)d_in[14];
  const float* bf1   = (const float*)d_in[15];
  const float* gamma = (const float*)d_in[16];
  const float* beta  = (const float*)d_in[17];
  const float* Wf2   = (const float*)d_in[18];
  const float* bf2   = (const float*)d_in[19];
  float* out = (float*)d_out;

  u16* wsb = (u16*)d_ws;
  float* wsf = (float*)((char*)d_ws + (size_t)END_BF16 * 2);
  float* att2 = wsf;
  float* bcat = wsf + 4;
  const size_t needed = (size_t)END_BF16 * 2 + (4 + 1536) * sizeof(float);
  if (ws_size < needed) return;  // ws too small; nothing safe to do

  hipMemsetAsync(att2, 0, 2 * sizeof(float), stream);
  k_cvt_x<<<dim3(1568, 2), 256, 0, stream>>>(rgb, dep, wsb);
  k_prep<<<2310, 256, 0, stream>>>(Wq_rd, Wk_r, Wv_r, Wq_dr, Wk_d, Wv_d, Wf1, Wf2,
                                   bq_rd, bk_r, bv_r, bq_dr, bk_d, bv_d, wsb, bcat);
  k_gemm<256, 0><<<dim3(49, 6, 4), 256, 0, stream>>>(wsb, bcat, nullptr, nullptr, nullptr, nullptr, nullptr);
  k_attn<<<dim3(49, 16, 2), 128, 0, stream>>>(wsb);
  k_amap_red<<<16, 256, 0, stream>>>(wsb, att2);
  k_amap_wr<<<dim3(13, 2), 256, 0, stream>>>(att2, out);
  k_gemm<512, 1><<<dim3(49, 2, 2), 256, 0, stream>>>(wsb, nullptr, bf1, gamma, beta, nullptr, nullptr);
  k_gemm<256, 2><<<dim3(49, 2, 2), 256, 0, stream>>>(wsb, nullptr, nullptr, nullptr, nullptr, bf2, out);
}